// Round 10
// baseline (1244.642 us; speedup 1.0000x reference)
//
#include <hip/hip_runtime.h>

typedef _Float16 f16;
typedef _Float16 f16x8 __attribute__((ext_vector_type(8)));
typedef float f32x4 __attribute__((ext_vector_type(4)));

#define T_STEPS 25
#define BATCH   4096
#define DIN     784
#define DH      1000
#define HP      1024
#define DOUT    10
#define MROWS   (T_STEPS * BATCH)   // 102400
#define KSEG    800
#define KB      (3 * KSEG)          // 2400 logical K
#define WROW    2432                // 38 * 64 (zero weights beyond 2400)
#define NT64    38

// ---------------------------------------------------------------------------
// Weights: Wh f16 [HP][2432] = [whi(800) | whi(800) | wlo(800) | 0(32)].
// ---------------------------------------------------------------------------
__global__ void wconv_kernel(const float* __restrict__ w1, const float* __restrict__ b1,
                             const float* __restrict__ w2,
                             f16* __restrict__ Wh, float* __restrict__ b1p,
                             float* __restrict__ w2t)
{
    const int stride = gridDim.x * blockDim.x;
    const int tid0 = blockIdx.x * blockDim.x + threadIdx.x;
    for (int idx = tid0; idx < HP * WROW; idx += stride) {
        const int n  = idx / WROW;
        const int k  = idx - n * WROW;
        f16 v = (f16)0.f;
        if (k < KB) {
            const int seg = k / KSEG;
            const int kc  = k - seg * KSEG;
            float w = (n < DH && kc < DIN) ? w1[n * DIN + kc] : 0.f;
            f16 h = (f16)w;
            v = (seg < 2) ? h : (f16)(w - (float)h);
        }
        Wh[idx] = v;
    }
    for (int idx = tid0; idx < HP; idx += stride)
        b1p[idx] = (idx < DH) ? b1[idx] : 0.f;
    for (int idx = tid0; idx < HP * DOUT; idx += stride) {
        const int h = idx / DOUT;
        const int o = idx - h * DOUT;
        w2t[idx] = (h < DH) ? w2[o * DH + h] : 0.f;
    }
}

// ---------------------------------------------------------------------------
// 256x256-tile GEMM, BK=64, dbuf-2 (128 KB LDS), r7 schedule verbatim,
// BUT A is staged straight from x (fp32) with in-register f16 hi/lo split
// (bitwise-identical to the old aconv pass -> absmax canary 0.03125):
//   logical A col c (tile-k + chunk): c<800 -> hi of x[:,c]; c>=800 -> lo of
//   x[:,c-800]; src col >=784 -> exact 0. ds_write_b128 to the same swizzled
//   phys slots global_load_lds used; drained by lgkmcnt(0) before the barrier.
// B still staged via global_load_lds from Wh. Grid: 400 mt x 4 nt = 1600.
// ---------------------------------------------------------------------------
#define GL(gp, ldsoff) __builtin_amdgcn_global_load_lds( \
    (const __attribute__((address_space(1))) void*)(gp), \
    (__attribute__((address_space(3))) void*)(lds + (ldsoff)), 16, 0, 0)

#define AKOF(tt) ((((tt) < 25) ? (tt) : ((tt) - 25)) * 64)

// B staging: 4 x global_load_lds (32 KB) into buf tt&1.
#define STAGE_B(tt) do { \
    const int _buf = ((tt) & 1) * 16384; \
    const int _bk  = (tt) * 64; \
    GL(Bg + _bk + 0 * 64 * WROW, 32768 + _buf + 0 * 4096 + widoff); \
    GL(Bg + _bk + 1 * 64 * WROW, 32768 + _buf + 1 * 4096 + widoff); \
    GL(Bg + _bk + 2 * 64 * WROW, 32768 + _buf + 2 * 4096 + widoff); \
    GL(Bg + _bk + 3 * 64 * WROW, 32768 + _buf + 3 * 4096 + widoff); } while (0)

// A source column math for tile tt (per-thread; pure function of tt).
#define ACOL(tt, c_, ldc_) \
    const int c_    = AKOF(tt) + gsw8; \
    const int _sc   = (c_ < 800) ? c_ : (c_ - 800); \
    const int ldc_  = (_sc < 784) ? _sc : 0;

// Issue A fp32 loads, groups 0-1 (rows 0-127 of the 256-row tile).
#define LOADA01(tt) do { ACOL(tt, _c, _ldc) \
    fa00 = *(const f32x4*)(Xrow + 0 * 64 * DIN + _ldc); \
    fa01 = *(const f32x4*)(Xrow + 0 * 64 * DIN + _ldc + 4); \
    fa10 = *(const f32x4*)(Xrow + 1 * 64 * DIN + _ldc); \
    fa11 = *(const f32x4*)(Xrow + 1 * 64 * DIN + _ldc + 4); } while (0)
// Groups 2-3 (rows 128-255).
#define LOADA23(tt) do { ACOL(tt, _c, _ldc) \
    fa20 = *(const f32x4*)(Xrow + 2 * 64 * DIN + _ldc); \
    fa21 = *(const f32x4*)(Xrow + 2 * 64 * DIN + _ldc + 4); \
    fa30 = *(const f32x4*)(Xrow + 3 * 64 * DIN + _ldc); \
    fa31 = *(const f32x4*)(Xrow + 3 * 64 * DIN + _ldc + 4); } while (0)

// Convert + swizzled ds_write (4 x b128). Compiler auto-waits the fa loads.
#define CVT8(w_, va, vb) do { \
    _Pragma("unroll") \
    for (int _j = 0; _j < 4; ++_j) { \
        float _v = va[_j]; \
        f16 _h = (f16)_v; \
        f16 _l = (f16)(_v - (float)_h); \
        w_[_j] = _pad ? (f16)0.f : (_lo ? _l : _h); \
    } \
    _Pragma("unroll") \
    for (int _j = 0; _j < 4; ++_j) { \
        float _v = vb[_j]; \
        f16 _h = (f16)_v; \
        f16 _l = (f16)(_v - (float)_h); \
        w_[4 + _j] = _pad ? (f16)0.f : (_lo ? _l : _h); \
    } } while (0)

#define CVTWR(tt) do { ACOL(tt, _c, _ldcu) (void)_ldcu; \
    const int _sc2  = (_c < 800) ? _c : (_c - 800); \
    const bool _lo  = (_c >= 800); \
    const bool _pad = (_sc2 >= 784); \
    const int _wb   = ((tt) & 1) * 16384 + tid * 8; \
    f16x8 w0, w1_, w2_, w3_; \
    CVT8(w0,  fa00, fa01); CVT8(w1_, fa10, fa11); \
    CVT8(w2_, fa20, fa21); CVT8(w3_, fa30, fa31); \
    *(f16x8*)(lds + _wb + 0 * 4096) = w0; \
    *(f16x8*)(lds + _wb + 1 * 4096) = w1_; \
    *(f16x8*)(lds + _wb + 2 * 4096) = w2_; \
    *(f16x8*)(lds + _wb + 3 * 4096) = w3_; } while (0)

#define MFMA16(A0, A1, A2, A3, B0, B1, B2, B3) \
    acc[0][0] = __builtin_amdgcn_mfma_f32_16x16x32_f16(A0, B0, acc[0][0], 0, 0, 0); \
    acc[0][1] = __builtin_amdgcn_mfma_f32_16x16x32_f16(A0, B1, acc[0][1], 0, 0, 0); \
    acc[0][2] = __builtin_amdgcn_mfma_f32_16x16x32_f16(A0, B2, acc[0][2], 0, 0, 0); \
    acc[0][3] = __builtin_amdgcn_mfma_f32_16x16x32_f16(A0, B3, acc[0][3], 0, 0, 0); \
    acc[1][0] = __builtin_amdgcn_mfma_f32_16x16x32_f16(A1, B0, acc[1][0], 0, 0, 0); \
    acc[1][1] = __builtin_amdgcn_mfma_f32_16x16x32_f16(A1, B1, acc[1][1], 0, 0, 0); \
    acc[1][2] = __builtin_amdgcn_mfma_f32_16x16x32_f16(A1, B2, acc[1][2], 0, 0, 0); \
    acc[1][3] = __builtin_amdgcn_mfma_f32_16x16x32_f16(A1, B3, acc[1][3], 0, 0, 0); \
    acc[2][0] = __builtin_amdgcn_mfma_f32_16x16x32_f16(A2, B0, acc[2][0], 0, 0, 0); \
    acc[2][1] = __builtin_amdgcn_mfma_f32_16x16x32_f16(A2, B1, acc[2][1], 0, 0, 0); \
    acc[2][2] = __builtin_amdgcn_mfma_f32_16x16x32_f16(A2, B2, acc[2][2], 0, 0, 0); \
    acc[2][3] = __builtin_amdgcn_mfma_f32_16x16x32_f16(A2, B3, acc[2][3], 0, 0, 0); \
    acc[3][0] = __builtin_amdgcn_mfma_f32_16x16x32_f16(A3, B0, acc[3][0], 0, 0, 0); \
    acc[3][1] = __builtin_amdgcn_mfma_f32_16x16x32_f16(A3, B1, acc[3][1], 0, 0, 0); \
    acc[3][2] = __builtin_amdgcn_mfma_f32_16x16x32_f16(A3, B2, acc[3][2], 0, 0, 0); \
    acc[3][3] = __builtin_amdgcn_mfma_f32_16x16x32_f16(A3, B3, acc[3][3], 0, 0, 0); \
    acc[4][0] = __builtin_amdgcn_mfma_f32_16x16x32_f16(A0, B0, acc[4][0], 0, 0, 0);
// (placeholder line above removed by not using acc[4]; see note below)

#undef MFMA16
#define MFMA16(A0, A1, A2, A3, B0, B1, B2, B3, M0) \
    acc[M0+0][0] = __builtin_amdgcn_mfma_f32_16x16x32_f16(A0, B0, acc[M0+0][0], 0, 0, 0); \
    acc[M0+0][1] = __builtin_amdgcn_mfma_f32_16x16x32_f16(A0, B1, acc[M0+0][1], 0, 0, 0); \
    acc[M0+0][2] = __builtin_amdgcn_mfma_f32_16x16x32_f16(A0, B2, acc[M0+0][2], 0, 0, 0); \
    acc[M0+0][3] = __builtin_amdgcn_mfma_f32_16x16x32_f16(A0, B3, acc[M0+0][3], 0, 0, 0); \
    acc[M0+1][0] = __builtin_amdgcn_mfma_f32_16x16x32_f16(A1, B0, acc[M0+1][0], 0, 0, 0); \
    acc[M0+1][1] = __builtin_amdgcn_mfma_f32_16x16x32_f16(A1, B1, acc[M0+1][1], 0, 0, 0); \
    acc[M0+1][2] = __builtin_amdgcn_mfma_f32_16x16x32_f16(A1, B2, acc[M0+1][2], 0, 0, 0); \
    acc[M0+1][3] = __builtin_amdgcn_mfma_f32_16x16x32_f16(A1, B3, acc[M0+1][3], 0, 0, 0); \
    acc[M0+2][0] = __builtin_amdgcn_mfma_f32_16x16x32_f16(A2, B0, acc[M0+2][0], 0, 0, 0); \
    acc[M0+2][1] = __builtin_amdgcn_mfma_f32_16x16x32_f16(A2, B1, acc[M0+2][1], 0, 0, 0); \
    acc[M0+2][2] = __builtin_amdgcn_mfma_f32_16x16x32_f16(A2, B2, acc[M0+2][2], 0, 0, 0); \
    acc[M0+2][3] = __builtin_amdgcn_mfma_f32_16x16x32_f16(A2, B3, acc[M0+2][3], 0, 0, 0); \
    acc[M0+3][0] = __builtin_amdgcn_mfma_f32_16x16x32_f16(A3, B0, acc[M0+3][0], 0, 0, 0); \
    acc[M0+3][1] = __builtin_amdgcn_mfma_f32_16x16x32_f16(A3, B1, acc[M0+3][1], 0, 0, 0); \
    acc[M0+3][2] = __builtin_amdgcn_mfma_f32_16x16x32_f16(A3, B2, acc[M0+3][2], 0, 0, 0); \
    acc[M0+3][3] = __builtin_amdgcn_mfma_f32_16x16x32_f16(A3, B3, acc[M0+3][3], 0, 0, 0);

#define RD(off) (*(const f16x8*)(lds + (off)))
#define LGKM(n) asm volatile("s_waitcnt lgkmcnt(" #n ")" ::: "memory")
#define SB      __builtin_amdgcn_sched_barrier(0)
#define P1      __builtin_amdgcn_s_setprio(1)
#define P0      __builtin_amdgcn_s_setprio(0)

// r7 BODY64 schedule with fused-A staging. Wave tile 128x64, acc[8][4].
#define BODY64(tt, STG) do { \
    const int bufc = ((tt) & 1) * 16384; \
    f16x8 a00, a01, a02, a03, b00, b01, b02, b03; \
    f16x8 a10, a11, a12, a13, b10, b11, b12, b13; \
    f16x8 c00, c01, c02, c03, c10, c11, c12, c13; \
    if (STG) { LOADA01((tt) + 1); STAGE_B((tt) + 1); } \
    b00 = RD(bbase + bufc + 0 * 1024 + cA0); \
    b01 = RD(bbase + bufc + 1 * 1024 + cA0); \
    b02 = RD(bbase + bufc + 2 * 1024 + cA0); \
    b03 = RD(bbase + bufc + 3 * 1024 + cA0); \
    a00 = RD(abase + bufc + 0 * 1024 + cA0); \
    a01 = RD(abase + bufc + 1 * 1024 + cA0); \
    a02 = RD(abase + bufc + 2 * 1024 + cA0); \
    a03 = RD(abase + bufc + 3 * 1024 + cA0); \
    a10 = RD(abase + bufc + 4 * 1024 + cA0); \
    a11 = RD(abase + bufc + 5 * 1024 + cA0); \
    a12 = RD(abase + bufc + 6 * 1024 + cA0); \
    a13 = RD(abase + bufc + 7 * 1024 + cA0); \
    LGKM(8); SB; \
    P1; MFMA16(a00, a01, a02, a03, b00, b01, b02, b03, 0) P0; \
    LGKM(0); SB; \
    b10 = RD(bbase + bufc + 0 * 1024 + cA1); \
    b11 = RD(bbase + bufc + 1 * 1024 + cA1); \
    b12 = RD(bbase + bufc + 2 * 1024 + cA1); \
    b13 = RD(bbase + bufc + 3 * 1024 + cA1); \
    c00 = RD(abase + bufc + 0 * 1024 + cA1); \
    c01 = RD(abase + bufc + 1 * 1024 + cA1); \
    c02 = RD(abase + bufc + 2 * 1024 + cA1); \
    c03 = RD(abase + bufc + 3 * 1024 + cA1); \
    c10 = RD(abase + bufc + 4 * 1024 + cA1); \
    c11 = RD(abase + bufc + 5 * 1024 + cA1); \
    c12 = RD(abase + bufc + 6 * 1024 + cA1); \
    c13 = RD(abase + bufc + 7 * 1024 + cA1); \
    SB; \
    P1; MFMA16(a10, a11, a12, a13, b00, b01, b02, b03, 4) P0; \
    if (STG) LOADA23((tt) + 1); \
    LGKM(4); SB; \
    P1; MFMA16(c00, c01, c02, c03, b10, b11, b12, b13, 0) P0; \
    LGKM(0); SB; \
    P1; MFMA16(c10, c11, c12, c13, b10, b11, b12, b13, 4) P0; \
    if (STG) { \
        CVTWR((tt) + 1);                                   /* auto vmcnt-wait on fa */ \
        asm volatile("s_waitcnt lgkmcnt(0)" ::: "memory"); /* ds_writes drained */ \
        asm volatile("s_waitcnt vmcnt(0)" ::: "memory");   /* B gloads drained */ \
        __builtin_amdgcn_s_barrier(); \
    } \
} while (0)

__global__ __launch_bounds__(512, 2)
void gemm_kernel(const float* __restrict__ X, const f16* __restrict__ B,
                 const float* __restrict__ bias, float* __restrict__ C)
{
    __shared__ f16 lds[65536];   // 128 KB: A dbuf [2][16384] | B dbuf at +32768

    const int bid = blockIdx.x;
    const int swz = (bid & 7) * 200 + (bid >> 3);   // bijective XCD chunking
    const int mt = swz >> 2;
    const int nt = swz & 3;
    const size_t rowBase = (size_t)mt * 256;
    const int colBase = nt * 256;

    const int tid  = threadIdx.x;
    const int wid  = tid >> 6;
    const int lane = tid & 63;
    const int wm = wid >> 2;      // 0..1
    const int wn = wid & 3;       // 0..3

    // staging geometry: row = tid>>3 (0..63) per 64-row group, phys chunk tid&7,
    // logical chunk gsw = (tid&7)^(row&7)  (r7-proven, 0 conflicts)
    const int trow = tid >> 3;
    const int gsw8 = ((tid & 7) ^ (trow & 7)) * 8;
    const float* Xrow = X + (rowBase + trow) * (size_t)DIN;
    const f16* Bg = B + (size_t)(colBase + trow) * WROW + gsw8;
    const int widoff = wid * 512;

    // ds_read constants: row stride 64 f16, chunk XOR (r&7)
    const int cA0 = (((lane >> 4))     ^ (lane & 7)) * 8;
    const int cA1 = (((lane >> 4) + 4) ^ (lane & 7)) * 8;
    const int abase = (wm * 128 + (lane & 15)) * 64;
    const int bbase = 32768 + (wn * 64 + (lane & 15)) * 64;

    f32x4 acc[8][4];
    #pragma unroll
    for (int m = 0; m < 8; ++m)
        #pragma unroll
        for (int n = 0; n < 4; ++n)
            acc[m][n] = (f32x4){0.f, 0.f, 0.f, 0.f};

    f32x4 fa00, fa01, fa10, fa11, fa20, fa21, fa30, fa31;

    // prologue: stage tile 0 (A from x + convert; B via gload_lds)
    LOADA01(0); LOADA23(0); STAGE_B(0);
    CVTWR(0);
    asm volatile("s_waitcnt lgkmcnt(0)" ::: "memory");
    asm volatile("s_waitcnt vmcnt(0)" ::: "memory");
    __builtin_amdgcn_s_barrier();

    for (int t = 0; t < NT64 - 1; ++t)
        BODY64(t, 1);
    BODY64(NT64 - 1, 0);

    // epilogue: C/D layout col = lane&15, row = (lane>>4)*4 + reg  [m89]
    const int c_col0 = colBase + wn * 64 + (lane & 15);
    const size_t c_row0 = rowBase + wm * 128 + (lane >> 4) * 4;
    #pragma unroll
    for (int n = 0; n < 4; ++n) {
        const int gcol = c_col0 + n * 16;
        const float bv = bias[gcol];
        #pragma unroll
        for (int m = 0; m < 8; ++m) {
            const size_t grow = c_row0 + m * 16;
            #pragma unroll
            for (int r = 0; r < 4; ++r)
                C[(grow + r) * HP + gcol] = acc[m][n][r] + bv;
        }
    }
}

// ---------------------------------------------------------------------------
// Temporal phase: per batch row, all 25 steps, mem1/mem2 in registers.
// ---------------------------------------------------------------------------
__global__ __launch_bounds__(256)
void phase2_kernel(const float* __restrict__ cur1, const float* __restrict__ w2t,
                   const float* __restrict__ b2, float* __restrict__ out)
{
    __shared__ float w2s[HP * DOUT];   // 40 KB
    const int tid = threadIdx.x;
    for (int i = tid; i < HP * DOUT; i += 256) w2s[i] = w2t[i];

    const int lane = tid & 63;
    const int wave = tid >> 6;
    const int b = blockIdx.x * 4 + wave;

    float m1[16];
    #pragma unroll
    for (int i = 0; i < 16; ++i) m1[i] = 0.f;
    float m2[DOUT], b2r[DOUT];
    #pragma unroll
    for (int o = 0; o < DOUT; ++o) { m2[o] = 0.f; b2r[o] = b2[o]; }
    __syncthreads();

    for (int t = 0; t < T_STEPS; ++t) {
        const float* cr = cur1 + ((size_t)t * BATCH + b) * HP;
        float p[DOUT];
        #pragma unroll
        for (int o = 0; o < DOUT; ++o) p[o] = 0.f;

        #pragma unroll
        for (int c = 0; c < 4; ++c) {
            const float4 cu = *(const float4*)(cr + c * 256 + lane * 4);
            const float cv[4] = {cu.x, cu.y, cu.z, cu.w};
            #pragma unroll
            for (int j = 0; j < 4; ++j) {
                const float mo = m1[c * 4 + j];
                const float rs = (mo > 1.0f) ? 1.0f : 0.0f;
                const float mn = 0.95f * mo + cv[j] - rs;
                m1[c * 4 + j] = mn;
                if (mn > 1.0f) {
                    const float* wr = w2s + (c * 256 + lane * 4 + j) * DOUT;
                    #pragma unroll
                    for (int o = 0; o < DOUT; ++o) p[o] += wr[o];
                }
            }
        }
        #pragma unroll
        for (int o = 0; o < DOUT; ++o) {
            float v = p[o];
            #pragma unroll
            for (int msk = 32; msk > 0; msk >>= 1) v += __shfl_xor(v, msk, 64);
            p[o] = v;
        }
        #pragma unroll
        for (int o = 0; o < DOUT; ++o) {
            const float cur2 = p[o] + b2r[o];
            const float mo = m2[o];
            const float rs = (mo > 1.0f) ? 1.0f : 0.0f;
            m2[o] = 0.95f * mo + cur2 - rs;
        }
        if (lane < DOUT)
            out[(size_t)t * (BATCH * DOUT) + (size_t)b * DOUT + lane] =
                (m2[lane] > 1.0f) ? 1.0f : 0.0f;
    }
    if (lane < DOUT)
        out[(size_t)T_STEPS * BATCH * DOUT + (size_t)b * DOUT + lane] = m2[lane];
}

// ---------------------------------------------------------------------------
extern "C" void kernel_launch(void* const* d_in, const int* in_sizes, int n_in,
                              void* d_out, int out_size, void* d_ws, size_t ws_size,
                              hipStream_t stream)
{
    const float* x  = (const float*)d_in[0];
    const float* w1 = (const float*)d_in[1];
    const float* b1 = (const float*)d_in[2];
    const float* w2 = (const float*)d_in[3];
    const float* b2 = (const float*)d_in[4];
    float* out = (float*)d_out;

    char* wsb = (char*)d_ws;
    f16*   Wh   = (f16*)(wsb);                                   //   4,980,736 B
    float* cur1 = (float*)(wsb + 4980736);                       // 419,430,400 B
    float* b1p  = (float*)(wsb + 4980736 + 419430400);
    float* w2t  = (float*)(wsb + 4980736 + 419430400 + 4096);

    wconv_kernel<<<1024, 256, 0, stream>>>(w1, b1, w2, Wh, b1p, w2t);
    gemm_kernel<<<1600, 512, 0, stream>>>(x, Wh, b1p, cur1);
    phase2_kernel<<<1024, 256, 0, stream>>>(cur1, w2t, b2, out);
}

// Round 11
// 759.712 us; speedup vs baseline: 1.6383x; 1.6383x over previous
//
#include <hip/hip_runtime.h>

typedef _Float16 f16;
typedef _Float16 f16x4 __attribute__((ext_vector_type(4)));
typedef _Float16 f16x8 __attribute__((ext_vector_type(8)));
typedef float f32x4 __attribute__((ext_vector_type(4)));

#define T_STEPS 25
#define BATCH   4096
#define DIN     784
#define DH      1000
#define HP      1024
#define DOUT    10
#define MROWS   (T_STEPS * BATCH)   // 102400
#define KSEG    800                 // 784 padded to 800
#define KA      (2 * KSEG)          // A width: [xhi | xlo] = 1600
#define KB      (3 * KSEG)          // real B width = 2400
#define WROW    2432                // Wh padded width: 38 * 64 (zeros beyond 2400)
#define NT64    38                  // K-tiles of 64

// ---------------------------------------------------------------------------
// Fused prep (one launch): Ah f16 [MROWS][1600] = [hi|lo] from x;
// Wh f16 [HP][2432] = [whi|whi|wlo|0]; b1p fp32 [HP]; w2t fp32 [HP][10].
// ---------------------------------------------------------------------------
__global__ void prep_kernel(const float* __restrict__ x, const float* __restrict__ w1,
                            const float* __restrict__ b1, const float* __restrict__ w2,
                            f16* __restrict__ Ah, f16* __restrict__ Wh,
                            float* __restrict__ b1p, float* __restrict__ w2t)
{
    const int stride = gridDim.x * blockDim.x;
    const int tid0 = blockIdx.x * blockDim.x + threadIdx.x;

    // Ah: 102400 rows x 200 chunks of 4 cols
    const int total = MROWS * 200;
    for (int idx = tid0; idx < total; idx += stride) {
        const int r  = idx / 200;
        const int c4 = (idx - r * 200) * 4;
        f16x4 hi, lo;
        if (c4 < DIN) {
            const float4 v = *(const float4*)(x + (size_t)r * DIN + c4);
            const float vv[4] = {v.x, v.y, v.z, v.w};
            #pragma unroll
            for (int j = 0; j < 4; ++j) {
                f16 h = (f16)vv[j];
                hi[j] = h;
                lo[j] = (f16)(vv[j] - (float)h);
            }
        } else {
            #pragma unroll
            for (int j = 0; j < 4; ++j) { hi[j] = (f16)0.f; lo[j] = (f16)0.f; }
        }
        *(f16x4*)(Ah + (size_t)r * KA + c4)        = hi;
        *(f16x4*)(Ah + (size_t)r * KA + KSEG + c4) = lo;
    }

    // Wh
    for (int idx = tid0; idx < HP * WROW; idx += stride) {
        const int n  = idx / WROW;
        const int k  = idx - n * WROW;
        f16 v = (f16)0.f;
        if (k < KB) {
            const int seg = k / KSEG;
            const int kc  = k - seg * KSEG;
            float w = (n < DH && kc < DIN) ? w1[n * DIN + kc] : 0.f;
            f16 h = (f16)w;
            v = (seg < 2) ? h : (f16)(w - (float)h);
        }
        Wh[idx] = v;
    }
    for (int idx = tid0; idx < HP; idx += stride)
        b1p[idx] = (idx < DH) ? b1[idx] : 0.f;
    for (int idx = tid0; idx < HP * DOUT; idx += stride) {
        const int h = idx / DOUT;
        const int o = idx - h * DOUT;
        w2t[idx] = (h < DH) ? w2[o * DH + h] : 0.f;
    }
}

// ---------------------------------------------------------------------------
// 256x256-tile GEMM, BK=64, dbuf-2 (128 KB LDS)  [r7 verbatim — best measured]
// Per K-64 body: 8 stage calls at TOP (covered vmcnt(0) at end), 24 ds_reads
// in two bursts of 12 with counted lgkmcnt(4)/(0), 4 x 16-MFMA sub-phases,
// ONE barrier. 8-chunk XOR swizzle (chunk ^ (row&7)) both-sides.
// K padded 2400->2432 with zero weights: tail products are exact zeros ->
// accumulation bitwise-identical to rounds 3-7 (absmax canary 0.03125).
// Grid: 400 mt x 4 nt = 1600 blocks.
// ---------------------------------------------------------------------------
#define GL(gp, ldsoff) __builtin_amdgcn_global_load_lds( \
    (const __attribute__((address_space(1))) void*)(gp), \
    (__attribute__((address_space(3))) void*)(lds + (ldsoff)), 16, 0, 0)

#define STAGE64(tt) do { \
    const int _buf = ((tt) & 1) * 16384; \
    const int _ak  = (((tt) < 25) ? (tt) : ((tt) - 25)) * 64; \
    const int _bk  = (tt) * 64; \
    GL(Ag + _ak + 0 * 64 * KA,   _buf + 0 * 4096 + widoff); \
    GL(Ag + _ak + 1 * 64 * KA,   _buf + 1 * 4096 + widoff); \
    GL(Ag + _ak + 2 * 64 * KA,   _buf + 2 * 4096 + widoff); \
    GL(Ag + _ak + 3 * 64 * KA,   _buf + 3 * 4096 + widoff); \
    GL(Bg + _bk + 0 * 64 * WROW, 32768 + _buf + 0 * 4096 + widoff); \
    GL(Bg + _bk + 1 * 64 * WROW, 32768 + _buf + 1 * 4096 + widoff); \
    GL(Bg + _bk + 2 * 64 * WROW, 32768 + _buf + 2 * 4096 + widoff); \
    GL(Bg + _bk + 3 * 64 * WROW, 32768 + _buf + 3 * 4096 + widoff); } while (0)

#define MFMA16(A0, A1, A2, A3, B0, B1, B2, B3, M0) \
    acc[M0+0][0] = __builtin_amdgcn_mfma_f32_16x16x32_f16(A0, B0, acc[M0+0][0], 0, 0, 0); \
    acc[M0+0][1] = __builtin_amdgcn_mfma_f32_16x16x32_f16(A0, B1, acc[M0+0][1], 0, 0, 0); \
    acc[M0+0][2] = __builtin_amdgcn_mfma_f32_16x16x32_f16(A0, B2, acc[M0+0][2], 0, 0, 0); \
    acc[M0+0][3] = __builtin_amdgcn_mfma_f32_16x16x32_f16(A0, B3, acc[M0+0][3], 0, 0, 0); \
    acc[M0+1][0] = __builtin_amdgcn_mfma_f32_16x16x32_f16(A1, B0, acc[M0+1][0], 0, 0, 0); \
    acc[M0+1][1] = __builtin_amdgcn_mfma_f32_16x16x32_f16(A1, B1, acc[M0+1][1], 0, 0, 0); \
    acc[M0+1][2] = __builtin_amdgcn_mfma_f32_16x16x32_f16(A1, B2, acc[M0+1][2], 0, 0, 0); \
    acc[M0+1][3] = __builtin_amdgcn_mfma_f32_16x16x32_f16(A1, B3, acc[M0+1][3], 0, 0, 0); \
    acc[M0+2][0] = __builtin_amdgcn_mfma_f32_16x16x32_f16(A2, B0, acc[M0+2][0], 0, 0, 0); \
    acc[M0+2][1] = __builtin_amdgcn_mfma_f32_16x16x32_f16(A2, B1, acc[M0+2][1], 0, 0, 0); \
    acc[M0+2][2] = __builtin_amdgcn_mfma_f32_16x16x32_f16(A2, B2, acc[M0+2][2], 0, 0, 0); \
    acc[M0+2][3] = __builtin_amdgcn_mfma_f32_16x16x32_f16(A2, B3, acc[M0+2][3], 0, 0, 0); \
    acc[M0+3][0] = __builtin_amdgcn_mfma_f32_16x16x32_f16(A3, B0, acc[M0+3][0], 0, 0, 0); \
    acc[M0+3][1] = __builtin_amdgcn_mfma_f32_16x16x32_f16(A3, B1, acc[M0+3][1], 0, 0, 0); \
    acc[M0+3][2] = __builtin_amdgcn_mfma_f32_16x16x32_f16(A3, B2, acc[M0+3][2], 0, 0, 0); \
    acc[M0+3][3] = __builtin_amdgcn_mfma_f32_16x16x32_f16(A3, B3, acc[M0+3][3], 0, 0, 0);

#define RD(off) (*(const f16x8*)(lds + (off)))

#define BODY64(tt, STG) do { \
    const int bufc = ((tt) & 1) * 16384; \
    f16x8 b00, b01, b02, b03, a00, a01, a02, a03, a10, a11, a12, a13; \
    f16x8 b10, b11, b12, b13, c00, c01, c02, c03, c10, c11, c12, c13; \
    if (STG) STAGE64((tt) + 1); \
    b00 = RD(bbase + bufc + 0 * 1024 + cA0); \
    b01 = RD(bbase + bufc + 1 * 1024 + cA0); \
    b02 = RD(bbase + bufc + 2 * 1024 + cA0); \
    b03 = RD(bbase + bufc + 3 * 1024 + cA0); \
    a00 = RD(abase + bufc + 0 * 1024 + cA0); \
    a01 = RD(abase + bufc + 1 * 1024 + cA0); \
    a02 = RD(abase + bufc + 2 * 1024 + cA0); \
    a03 = RD(abase + bufc + 3 * 1024 + cA0); \
    a10 = RD(abase + bufc + 4096 + 0 * 1024 + cA0); \
    a11 = RD(abase + bufc + 4096 + 1 * 1024 + cA0); \
    a12 = RD(abase + bufc + 4096 + 2 * 1024 + cA0); \
    a13 = RD(abase + bufc + 4096 + 3 * 1024 + cA0); \
    asm volatile("s_waitcnt lgkmcnt(4)" ::: "memory");  /* b0*,a0* landed */ \
    __builtin_amdgcn_sched_barrier(0); \
    __builtin_amdgcn_s_setprio(1); \
    MFMA16(a00, a01, a02, a03, b00, b01, b02, b03, 0) \
    __builtin_amdgcn_s_setprio(0); \
    asm volatile("s_waitcnt lgkmcnt(0)" ::: "memory");  /* a1* landed */ \
    __builtin_amdgcn_sched_barrier(0); \
    b10 = RD(bbase + bufc + 0 * 1024 + cA1); \
    b11 = RD(bbase + bufc + 1 * 1024 + cA1); \
    b12 = RD(bbase + bufc + 2 * 1024 + cA1); \
    b13 = RD(bbase + bufc + 3 * 1024 + cA1); \
    c00 = RD(abase + bufc + 0 * 1024 + cA1); \
    c01 = RD(abase + bufc + 1 * 1024 + cA1); \
    c02 = RD(abase + bufc + 2 * 1024 + cA1); \
    c03 = RD(abase + bufc + 3 * 1024 + cA1); \
    c10 = RD(abase + bufc + 4096 + 0 * 1024 + cA1); \
    c11 = RD(abase + bufc + 4096 + 1 * 1024 + cA1); \
    c12 = RD(abase + bufc + 4096 + 2 * 1024 + cA1); \
    c13 = RD(abase + bufc + 4096 + 3 * 1024 + cA1); \
    __builtin_amdgcn_sched_barrier(0); \
    __builtin_amdgcn_s_setprio(1); \
    MFMA16(a10, a11, a12, a13, b00, b01, b02, b03, 4) \
    __builtin_amdgcn_s_setprio(0); \
    asm volatile("s_waitcnt lgkmcnt(4)" ::: "memory");  /* b1*,c0* landed */ \
    __builtin_amdgcn_sched_barrier(0); \
    __builtin_amdgcn_s_setprio(1); \
    MFMA16(c00, c01, c02, c03, b10, b11, b12, b13, 0) \
    __builtin_amdgcn_s_setprio(0); \
    asm volatile("s_waitcnt lgkmcnt(0)" ::: "memory");  /* c1* landed */ \
    __builtin_amdgcn_sched_barrier(0); \
    __builtin_amdgcn_s_setprio(1); \
    MFMA16(c10, c11, c12, c13, b10, b11, b12, b13, 4) \
    __builtin_amdgcn_s_setprio(0); \
    if (STG) { \
        asm volatile("s_waitcnt vmcnt(0)" ::: "memory");  /* covered: issued at body top */ \
        __builtin_amdgcn_s_barrier(); \
    } \
} while (0)

__global__ __launch_bounds__(512, 2)
void gemm_kernel(const f16* __restrict__ A, const f16* __restrict__ B,
                 const float* __restrict__ bias, float* __restrict__ C)
{
    __shared__ f16 lds[65536];   // 128 KB: A dbuf [2][16384] | B dbuf at +32768

    const int bid = blockIdx.x;
    const int swz = (bid & 7) * 200 + (bid >> 3);   // bijective XCD chunking
    const int mt = swz >> 2;
    const int nt = swz & 3;
    const size_t rowBase = (size_t)mt * 256;
    const int colBase = nt * 256;

    const int tid  = threadIdx.x;
    const int wid  = tid >> 6;
    const int lane = tid & 63;
    const int wm = wid >> 2;      // 0..1
    const int wn = wid & 3;       // 0..3

    // staging: row = tid>>3 within 64-row slab, pre-swizzled chunk ^ (row&7)
    const int gsw = (tid & 7) ^ ((tid >> 3) & 7);
    const f16* Ag = A + (rowBase + (tid >> 3)) * KA + gsw * 8;
    const f16* Bg = B + (size_t)(colBase + (tid >> 3)) * WROW + gsw * 8;
    const int widoff = wid * 512;   // wave-uniform LDS base (1 KB/wave)

    // ds_read constants: row stride 64 f16 (128 B), 8-chunk XOR
    const int cA0 = (((lane >> 4))     ^ (lane & 7)) * 8;
    const int cA1 = (((lane >> 4) + 4) ^ (lane & 7)) * 8;
    const int abase = (wm * 128 + (lane & 15)) * 64;
    const int bbase = 32768 + (wn * 64 + (lane & 15)) * 64;

    f32x4 acc[8][4];
    #pragma unroll
    for (int m = 0; m < 8; ++m)
        #pragma unroll
        for (int n = 0; n < 4; ++n)
            acc[m][n] = (f32x4){0.f, 0.f, 0.f, 0.f};

    // prologue: stage tile 0, drain, barrier
    STAGE64(0);
    asm volatile("s_waitcnt vmcnt(0)" ::: "memory");
    __builtin_amdgcn_s_barrier();

    for (int t = 0; t < NT64 - 1; ++t)   // bodies 0..36 stage t+1
        BODY64(t, 1);
    BODY64(NT64 - 1, 0);                 // body 37: no stage, no barrier

    // epilogue: C/D layout col = lane&15, row = (lane>>4)*4 + reg  [m89]
    const int c_col0 = colBase + wn * 64 + (lane & 15);
    const size_t c_row0 = rowBase + wm * 128 + (lane >> 4) * 4;
    #pragma unroll
    for (int n = 0; n < 4; ++n) {
        const int gcol = c_col0 + n * 16;
        const float bv = bias[gcol];
        #pragma unroll
        for (int m = 0; m < 8; ++m) {
            const size_t grow = c_row0 + m * 16;
            #pragma unroll
            for (int r = 0; r < 4; ++r)
                C[(grow + r) * HP + gcol] = acc[m][n][r] + bv;
        }
    }
}

// ---------------------------------------------------------------------------
// Temporal phase: per batch row, all 25 steps, mem1/mem2 in registers.
// ---------------------------------------------------------------------------
__global__ __launch_bounds__(256)
void phase2_kernel(const float* __restrict__ cur1, const float* __restrict__ w2t,
                   const float* __restrict__ b2, float* __restrict__ out)
{
    __shared__ float w2s[HP * DOUT];   // 40 KB
    const int tid = threadIdx.x;
    for (int i = tid; i < HP * DOUT; i += 256) w2s[i] = w2t[i];

    const int lane = tid & 63;
    const int wave = tid >> 6;
    const int b = blockIdx.x * 4 + wave;

    float m1[16];
    #pragma unroll
    for (int i = 0; i < 16; ++i) m1[i] = 0.f;
    float m2[DOUT], b2r[DOUT];
    #pragma unroll
    for (int o = 0; o < DOUT; ++o) { m2[o] = 0.f; b2r[o] = b2[o]; }
    __syncthreads();

    for (int t = 0; t < T_STEPS; ++t) {
        const float* cr = cur1 + ((size_t)t * BATCH + b) * HP;
        float p[DOUT];
        #pragma unroll
        for (int o = 0; o < DOUT; ++o) p[o] = 0.f;

        #pragma unroll
        for (int c = 0; c < 4; ++c) {
            const float4 cu = *(const float4*)(cr + c * 256 + lane * 4);
            const float cv[4] = {cu.x, cu.y, cu.z, cu.w};
            #pragma unroll
            for (int j = 0; j < 4; ++j) {
                const float mo = m1[c * 4 + j];
                const float rs = (mo > 1.0f) ? 1.0f : 0.0f;
                const float mn = 0.95f * mo + cv[j] - rs;
                m1[c * 4 + j] = mn;
                if (mn > 1.0f) {
                    const float* wr = w2s + (c * 256 + lane * 4 + j) * DOUT;
                    #pragma unroll
                    for (int o = 0; o < DOUT; ++o) p[o] += wr[o];
                }
            }
        }
        #pragma unroll
        for (int o = 0; o < DOUT; ++o) {
            float v = p[o];
            #pragma unroll
            for (int msk = 32; msk > 0; msk >>= 1) v += __shfl_xor(v, msk, 64);
            p[o] = v;
        }
        #pragma unroll
        for (int o = 0; o < DOUT; ++o) {
            const float cur2 = p[o] + b2r[o];
            const float mo = m2[o];
            const float rs = (mo > 1.0f) ? 1.0f : 0.0f;
            m2[o] = 0.95f * mo + cur2 - rs;
        }
        if (lane < DOUT)
            out[(size_t)t * (BATCH * DOUT) + (size_t)b * DOUT + lane] =
                (m2[lane] > 1.0f) ? 1.0f : 0.0f;
    }
    if (lane < DOUT)
        out[(size_t)T_STEPS * BATCH * DOUT + (size_t)b * DOUT + lane] = m2[lane];
}

// ---------------------------------------------------------------------------
extern "C" void kernel_launch(void* const* d_in, const int* in_sizes, int n_in,
                              void* d_out, int out_size, void* d_ws, size_t ws_size,
                              hipStream_t stream)
{
    const float* x  = (const float*)d_in[0];
    const float* w1 = (const float*)d_in[1];
    const float* b1 = (const float*)d_in[2];
    const float* w2 = (const float*)d_in[3];
    const float* b2 = (const float*)d_in[4];
    float* out = (float*)d_out;

    char* wsb = (char*)d_ws;
    f16*   Ah   = (f16*)(wsb);                                   // 327,680,000 B
    f16*   Wh   = (f16*)(wsb + 327680000);                       //   4,980,736 B
    float* cur1 = (float*)(wsb + 327680000 + 4980736);           // 419,430,400 B
    float* b1p  = (float*)(wsb + 327680000 + 4980736 + 419430400);
    float* w2t  = (float*)(wsb + 327680000 + 4980736 + 419430400 + 4096);

    prep_kernel<<<4096, 256, 0, stream>>>(x, w1, b1, w2, Ah, Wh, b1p, w2t);
    gemm_kernel<<<1600, 512, 0, stream>>>(Ah, Wh, b1p, cur1);
    phase2_kernel<<<1024, 256, 0, stream>>>(cur1, w2t, b2, out);
}